// Round 10
// baseline (642.362 us; speedup 1.0000x reference)
//
#include <hip/hip_runtime.h>
#include <hip/hip_bf16.h>
#include <stdint.h>

#define NN 100000
#define NE 1600000
#define FIN 100
#define HID 128
#define CLS 47
#define NBUK 391            // ceil(NN/256) buckets of 256 nodes
#define NPOS 100032         // NN padded to 64-node groups
#define SLB ((size_t)NN * 32)   // bytes per 16-col slice of one activation matrix

typedef __attribute__((ext_vector_type(8))) short bf16x8;
typedef __attribute__((ext_vector_type(4))) float f32x4;

#define AS1(p) ((const __attribute__((address_space(1))) void*)(p))
#define AS3(p) ((__attribute__((address_space(3))) void*)(p))

__device__ __forceinline__ uint16_t f2bf(float f) {
  union { float f; uint32_t u; } v; v.f = f;
  uint32_t r = v.u + 0x7fffu + ((v.u >> 16) & 1u);
  return (uint16_t)(r >> 16);
}

// sliced positional layout: element (pos, col) at base + (col>>4)*SLB + pos*32 + (col&15)*2
__device__ __forceinline__ const char* xsrc(const char* base, int row, int col) {
  return base + (size_t)(col >> 4) * SLB + (size_t)row * 32 + (size_t)(col & 15) * 2;
}
__device__ __forceinline__ char* xdst(char* base, int row, int col) {
  return base + (size_t)(col >> 4) * SLB + (size_t)row * 32 + (size_t)(col & 15) * 2;
}

// ---- weight packing: B_l[j][k] (128 x 256) bf16; k<128 -> W_rel, k>=128 -> W_root (layer1 zero-padded)
__global__ void pack_weights(const float* __restrict__ W1r, const float* __restrict__ W1o,
                             const float* __restrict__ W2r, const float* __restrict__ W2o,
                             const float* __restrict__ W3r, const float* __restrict__ W3o,
                             uint16_t* __restrict__ B1, uint16_t* __restrict__ B2, uint16_t* __restrict__ B3) {
  int idx = blockIdx.x * 256 + threadIdx.x;      // < 3*128*256
  int l = idx >> 15;
  int rem = idx & 32767;
  int j = rem >> 8;
  int k = rem & 255;
  if (l == 0) {
    uint16_t v = 0;
    if (k < FIN) v = f2bf(W1r[j*FIN + k]);
    else if (k >= 128 && k < 128 + FIN) v = f2bf(W1o[j*FIN + (k - 128)]);
    B1[j*256 + k] = v;
  } else if (l == 1) {
    B2[j*256 + k] = (k < 128) ? f2bf(W2r[j*128 + k]) : f2bf(W2o[j*128 + (k - 128)]);
  } else {
    B3[j*256 + k] = (k < 128) ? f2bf(W3r[j*128 + k]) : f2bf(W3o[j*128 + (k - 128)]);
  }
}

// ---- W_lin [47,384] f32 -> Wlb [48,384] bf16 (row 47 zero)
__global__ void pack_wl(const float* __restrict__ Wl, uint16_t* __restrict__ Wlb) {
  int idx = blockIdx.x * 256 + threadIdx.x;      // < 48*384
  int r = idx / 384;
  int c = idx - r * 384;
  Wlb[idx] = (r < CLS) ? f2bf(Wl[r*384 + c]) : (uint16_t)0;
}

// ---- pad+convert x0 row perm[p] -> position p, sliced bf16; 4 positions/block
__global__ __launch_bounds__(256) void pad_x0(const float* __restrict__ x0, const int* __restrict__ perm,
                                              char* __restrict__ xs) {
  int p = blockIdx.x * 4 + (threadIdx.x >> 6);
  int n = perm[p];                               // grid = NN/4 exactly
  int c = 2 * (threadIdx.x & 63);
  uint32_t o = 0;
  if (c < FIN) {
    float2 v = *(const float2*)(x0 + (size_t)n*FIN + c);
    o = ((uint32_t)f2bf(v.y) << 16) | (uint32_t)f2bf(v.x);
  }
  *(uint32_t*)xdst(xs, p, c) = o;
}

// ======== binned CSR build ========
__global__ __launch_bounds__(512) void bucket_hist(const int* __restrict__ dst, int* __restrict__ bcnt) {
  __shared__ int h[NBUK];
  int tid = threadIdx.x;
  for (int i = tid; i < NBUK; i += 512) h[i] = 0;
  __syncthreads();
  int tile0 = blockIdx.x * 8192;
  int n = NE - tile0; if (n > 8192) n = 8192;
  for (int i = tid; i < n; i += 512) atomicAdd(&h[dst[tile0 + i] >> 8], 1);
  __syncthreads();
  for (int i = tid; i < NBUK; i += 512) if (h[i]) atomicAdd(&bcnt[i], h[i]);
}

__global__ __launch_bounds__(512) void bucket_scan(const int* __restrict__ bcnt,
                                                   int* __restrict__ bfill, int* __restrict__ bbase) {
  __shared__ int sh[512];
  int t = threadIdx.x;
  int v = (t < NBUK) ? bcnt[t] : 0;
  sh[t] = v;
  __syncthreads();
  for (int off = 1; off < 512; off <<= 1) {
    int tv = (t >= off) ? sh[t - off] : 0;
    __syncthreads();
    sh[t] += tv;
    __syncthreads();
  }
  if (t < NBUK) {
    int e = sh[t] - v;
    bfill[t] = e;
    bbase[t] = e;
  }
  if (t == 0) bbase[NBUK] = NE;
}

// Packed rec: x = src | dstLocal<<17 (src<2^17, dstLocal<256), y = weight bits.
__global__ __launch_bounds__(512) void binscat(const int* __restrict__ src, const int* __restrict__ dst,
                                               const float* __restrict__ ew,
                                               int* __restrict__ bfill, int2* __restrict__ ebin) {
  __shared__ int h[NBUK];
  __shared__ int base[NBUK];
  int tid = threadIdx.x;
  for (int i = tid; i < NBUK; i += 512) h[i] = 0;
  __syncthreads();
  int tile0 = blockIdx.x * 8192;
  int n = NE - tile0; if (n > 8192) n = 8192;
  for (int i = tid; i < n; i += 512) atomicAdd(&h[dst[tile0 + i] >> 8], 1);
  __syncthreads();
  for (int i = tid; i < NBUK; i += 512) base[i] = h[i] ? atomicAdd(&bfill[i], h[i]) : 0;
  __syncthreads();
  for (int i = tid; i < NBUK; i += 512) h[i] = 0;
  __syncthreads();
  for (int i = tid; i < n; i += 512) {
    int e = tile0 + i;
    int d = dst[e];
    int b = d >> 8;
    int r = atomicAdd(&h[b], 1);
    ebin[base[b] + r] = make_int2(src[e] | ((d & 255) << 17), __float_as_int(ew[e]));
  }
}

// Stage 4: one block per bucket. Emits row_start (node order), packed edges
//   epack = src<<15 | bf16(w), and the per-bucket degree-sorted perm.
__global__ __launch_bounds__(256) void bucket_csr(const int2* __restrict__ ebin,
                                                  const int* __restrict__ bbase,
                                                  int* __restrict__ row_start,
                                                  uint32_t* __restrict__ epack,
                                                  int* __restrict__ perm) {
  __shared__ int sh[256];
  __shared__ int fill[256];
  __shared__ int dh[64];
  __shared__ int doff[64];
  int b = blockIdx.x;
  int tid = threadIdx.x;
  int ebase = bbase[b], eend = bbase[b + 1];
  int cnt = eend - ebase;
  sh[tid] = 0;
  if (tid < 64) dh[tid] = 0;
  __syncthreads();
  for (int i = tid; i < cnt; i += 256) atomicAdd(&sh[(uint32_t)ebin[ebase + i].x >> 17], 1);
  __syncthreads();
  int histv = sh[tid];
  __syncthreads();
  for (int off = 1; off < 256; off <<= 1) {
    int tv = (tid >= off) ? sh[tid - off] : 0;
    __syncthreads();
    sh[tid] += tv;
    __syncthreads();
  }
  int excl = sh[tid] - histv;
  int node = b * 256 + tid;
  bool valid = node < NN;
  if (node <= NN) row_start[node] = ebase + excl;
  fill[tid] = ebase + excl;

  int dbin = histv > 63 ? 63 : histv;
  int lrank = 0;
  if (valid) lrank = atomicAdd(&dh[dbin], 1);
  __syncthreads();
  if (tid < 64) {
    int v = dh[tid];
    int x = v;
    #pragma unroll
    for (int off = 1; off < 64; off <<= 1) {
      int y = __shfl_up(x, off, 64);
      if (tid >= off) x += y;
    }
    doff[tid] = x - v;
  }
  __syncthreads();
  if (valid) perm[b * 256 + doff[dbin] + lrank] = node;

  for (int i = tid; i < cnt; i += 256) {
    int2 rec = ebin[ebase + i];
    int dl = (uint32_t)rec.x >> 17;
    uint32_t s = (uint32_t)rec.x & 0x1FFFFu;
    int pos = atomicAdd(&fill[dl], 1);
    epack[pos] = (s << 15) | (uint32_t)f2bf(__int_as_float(rec.y));
  }
}

// ---- perm helpers: ipos = inverse perm; remap epack src node->position;
//      rspos[p] = {edge start, degree} so spmm needs one 8B load per node
__global__ void ipos_build(const int* __restrict__ perm, int* __restrict__ ipos) {
  int p = blockIdx.x * 256 + threadIdx.x;
  if (p < NN) ipos[perm[p]] = p;
}

__global__ void epack_remap(uint32_t* __restrict__ epack, const int* __restrict__ ipos) {
  int e = blockIdx.x * 256 + threadIdx.x;
  if (e < NE) {
    uint32_t rec = epack[e];
    epack[e] = ((uint32_t)ipos[rec >> 15] << 15) | (rec & 0x7FFFu);
  }
}

__global__ void rspos_build(const int* __restrict__ row_start, const int* __restrict__ perm,
                            int2* __restrict__ rspos) {
  int p = blockIdx.x * 256 + threadIdx.x;
  if (p >= NPOS) return;
  if (p < NN) {
    int n = perm[p];
    int r0 = row_start[n];
    rspos[p] = make_int2(r0, row_start[n + 1] - r0);
  } else {
    rspos[p] = make_int2(0, 0);
  }
}

// ---- SpMM (XCD-sliced, positional): agg[p, slice s] = sum_e w_e * x[srcpos_e, slice s]
// 16 nodes/wave x 4 lanes x 8B (dwordx2): half the VMEM instrs, ~1.6x fewer VALU
// per edge than 8x4B. Unclamped epack reads (affine -> offset-folded); garbage
// recs killed by w=0, gather offset masked <=4.2MB stays inside workspace.
__global__ __launch_bounds__(256) void spmm_kernel(const char* __restrict__ xs,
                                                   const int2* __restrict__ rspos,
                                                   const uint32_t* __restrict__ epack,
                                                   char* __restrict__ aggs) {
  int b = blockIdx.x;
  int s = b & 7;
  int g = b >> 3;
  int lane = threadIdx.x & 63;
  int wave = threadIdx.x >> 6;
  int nu = lane >> 2;
  int c8 = (lane & 3) * 8;
  const char* xsl = xs + (size_t)s * SLB;
  char* asl = aggs + (size_t)s * SLB;
  int p = g * 64 + wave * 16 + nu;
  int2 rs = rspos[p];
  int rs0 = rs.x, d = rs.y;

  float a0 = 0.f, a1 = 0.f, a2 = 0.f, a3 = 0.f;
  for (int j = 0; ; j += 8) {
    if (!__ballot(j < d)) break;
    uint32_t rec[8];
    const uint32_t* ep = epack + rs0 + j;
    #pragma unroll
    for (int u = 0; u < 8; ++u) rec[u] = ep[u];
    uint2 pr[8];
    #pragma unroll
    for (int u = 0; u < 8; ++u) {
      uint32_t boff = (rec[u] >> 10) & 0x003FFFE0u;   // srcpos*32
      pr[u] = *(const uint2*)(xsl + boff + c8);
    }
    #pragma unroll
    for (int u = 0; u < 8; ++u) {
      float w = __int_as_float((rec[u] << 16) & 0x7FFF0000u);
      if (j + u >= d) w = 0.f;
      union { uint32_t u32; float f; } q;
      q.u32 = pr[u].x << 16;         a0 += w * q.f;
      q.u32 = pr[u].x & 0xFFFF0000u; a1 += w * q.f;
      q.u32 = pr[u].y << 16;         a2 += w * q.f;
      q.u32 = pr[u].y & 0xFFFF0000u; a3 += w * q.f;
    }
  }
  if (p < NN) {
    uint2 o;
    o.x = ((uint32_t)f2bf(a1) << 16) | (uint32_t)f2bf(a0);
    o.y = ((uint32_t)f2bf(a3) << 16) | (uint32_t)f2bf(a2);
    *(uint2*)(asl + (size_t)p * 32 + c8) = o;      // contiguous positional store
  }
}

// ---- fused GEMM: out = relu([A1|A2] @ B^T + bias); positional sliced bf16 in/out
__global__ __launch_bounds__(256) void gemm_kernel(const char* __restrict__ A1, const char* __restrict__ A2,
                                                   const uint16_t* __restrict__ Bm, const float* __restrict__ bias,
                                                   char* __restrict__ out) {
  __shared__ uint16_t ldsA[128 * 32];
  __shared__ uint16_t ldsB[128 * 32];
  int t = threadIdx.x;
  int n0 = blockIdx.x * 128;
  int lane = t & 63, wave = t >> 6;
  int wm = (wave >> 1) * 64, wn = (wave & 1) * 64;
  int l15 = lane & 15, quad = lane >> 4;

  f32x4 acc[4][4];
  #pragma unroll
  for (int i = 0; i < 4; ++i)
    #pragma unroll
    for (int j = 0; j < 4; ++j) acc[i][j] = (f32x4){0.f, 0.f, 0.f, 0.f};

  for (int kt = 0; kt < 8; ++kt) {
    int kbase = kt * 32;
    const char* Asrc = (kbase < 128) ? A1 : A2;
    int klocal = kbase & 127;
    #pragma unroll
    for (int q = 0; q < 2; ++q) {
      int u = t + q * 256;                 // 0..511
      int r = u >> 2;                      // 0..127
      int kg = (u & 3) * 8;
      int rowA = n0 + r; if (rowA >= NN) rowA = NN - 1;
      __builtin_amdgcn_global_load_lds(AS1(xsrc(Asrc, rowA, klocal + kg)), AS3(&ldsA[u * 8]), 16, 0, 0);
      __builtin_amdgcn_global_load_lds(AS1(Bm + r*256 + kbase + kg), AS3(&ldsB[u * 8]), 16, 0, 0);
    }
    __syncthreads();
    bf16x8 af[4], bfr[4];
    #pragma unroll
    for (int mi = 0; mi < 4; ++mi) af[mi] = *(const bf16x8*)&ldsA[(wm + mi*16 + l15) * 32 + quad * 8];
    #pragma unroll
    for (int ni = 0; ni < 4; ++ni) bfr[ni] = *(const bf16x8*)&ldsB[(wn + ni*16 + l15) * 32 + quad * 8];
    #pragma unroll
    for (int mi = 0; mi < 4; ++mi)
      #pragma unroll
      for (int ni = 0; ni < 4; ++ni)
        acc[mi][ni] = __builtin_amdgcn_mfma_f32_16x16x32_bf16(af[mi], bfr[ni], acc[mi][ni], 0, 0, 0);
    __syncthreads();
  }

  #pragma unroll
  for (int mi = 0; mi < 4; ++mi) {
    #pragma unroll
    for (int ni = 0; ni < 4; ++ni) {
      int c = wn + ni*16 + l15;
      float bc = bias[c];
      #pragma unroll
      for (int i = 0; i < 4; ++i) {
        int r = n0 + wm + mi*16 + quad*4 + i;
        if (r < NN) {
          float v = acc[mi][ni][i] + bc;
          v = v > 0.f ? v : 0.f;
          *(uint16_t*)xdst(out, r, c) = f2bf(v);
        }
      }
    }
  }
}

// ---- final: positional rows; output row mapped back through perm
__global__ __launch_bounds__(256) void final_kernel(const char* __restrict__ x1, const char* __restrict__ x2,
                                                    const char* __restrict__ x3,
                                                    const uint16_t* __restrict__ Wlb, const float* __restrict__ bl,
                                                    const int* __restrict__ perm,
                                                    float* __restrict__ out) {
  int t = threadIdx.x;
  int lane = t & 63, wave = t >> 6;
  int n0 = blockIdx.x * 64 + wave * 16;
  int l15 = lane & 15, quad = lane >> 4;

  f32x4 acc[3];
  #pragma unroll
  for (int i = 0; i < 3; ++i) acc[i] = (f32x4){0.f, 0.f, 0.f, 0.f};

  int arow = n0 + l15; if (arow >= NN) arow = NN - 1;

  #pragma unroll
  for (int kt = 0; kt < 12; ++kt) {
    const char* xs = (kt < 4) ? x1 : (kt < 8) ? x2 : x3;
    int klocal = (kt & 3) * 32 + quad * 8;
    bf16x8 af = *(const bf16x8*)xsrc(xs, arow, klocal);
    int kglob = kt * 32 + quad * 8;
    #pragma unroll
    for (int nt = 0; nt < 3; ++nt) {
      int c = nt*16 + l15;                 // < 48, row 47 of Wlb is zero
      bf16x8 bfr = *(const bf16x8*)(Wlb + (size_t)c*(3*HID) + kglob);
      acc[nt] = __builtin_amdgcn_mfma_f32_16x16x32_bf16(af, bfr, acc[nt], 0, 0, 0);
    }
  }

  float bias[3]; bool valid[3];
  #pragma unroll
  for (int nt = 0; nt < 3; ++nt) {
    int c = nt*16 + l15;
    valid[nt] = (c < CLS);
    bias[nt] = valid[nt] ? bl[c] : 0.f;
  }

  #pragma unroll
  for (int i = 0; i < 4; ++i) {
    int r = n0 + quad*4 + i;
    float v0 = acc[0][i] + bias[0];
    float v1 = acc[1][i] + bias[1];
    float v2 = valid[2] ? (acc[2][i] + bias[2]) : -INFINITY;
    float m = fmaxf(v0, fmaxf(v1, v2));
    #pragma unroll
    for (int off = 8; off >= 1; off >>= 1) m = fmaxf(m, __shfl_xor(m, off, 64));
    float s = __expf(v0 - m) + __expf(v1 - m) + (valid[2] ? __expf(v2 - m) : 0.f);
    #pragma unroll
    for (int off = 8; off >= 1; off >>= 1) s += __shfl_xor(s, off, 64);
    float lse = m + __logf(s);
    if (r < NN) {
      int n = perm[r];
      out[(size_t)n*CLS + l15]      = v0 - lse;
      out[(size_t)n*CLS + 16 + l15] = v1 - lse;
      if (valid[2]) out[(size_t)n*CLS + 32 + l15] = v2 - lse;
    }
  }
}

extern "C" void kernel_launch(void* const* d_in, const int* in_sizes, int n_in,
                              void* d_out, int out_size, void* d_ws, size_t ws_size,
                              hipStream_t stream) {
  (void)in_sizes; (void)n_in; (void)out_size; (void)ws_size;
  const float* x0  = (const float*)d_in[0];
  const int*   ei  = (const int*)d_in[1];
  const float* ew  = (const float*)d_in[2];
  const float* W1r = (const float*)d_in[3];
  const float* W1o = (const float*)d_in[4];
  const float* b1  = (const float*)d_in[5];
  const float* W2r = (const float*)d_in[6];
  const float* W2o = (const float*)d_in[7];
  const float* b2  = (const float*)d_in[8];
  const float* W3r = (const float*)d_in[9];
  const float* W3o = (const float*)d_in[10];
  const float* b3  = (const float*)d_in[11];
  const float* Wl  = (const float*)d_in[12];
  const float* bl  = (const float*)d_in[13];
  const int* src = ei;
  const int* dst = ei + NE;

  char* ws = (char*)d_ws;
  size_t off = 0;
  auto alloc = [&](size_t bytes) -> void* {
    void* p = ws + off;
    off += (bytes + 255) & ~(size_t)255;
    return p;
  };
  char* x0p = (char*)alloc(SLB * 8);   // positional sliced activations; reused as xb2
  char* xb1 = (char*)alloc(SLB * 8);
  char* xb3 = (char*)alloc(SLB * 8);
  char* agg = (char*)alloc(SLB * 8);
  uint32_t* epack    = (uint32_t*)alloc((size_t)NE * 4 + 512);  // +guard for unclamped reads
  int2*   ebin      = (int2*)alloc((size_t)NE * 8);
  int*    row_start = (int*)alloc((size_t)(NN + 1) * 4);
  int*    perm      = (int*)alloc((size_t)NN * 4);
  int*    ipos      = (int*)alloc((size_t)NN * 4);
  int2*   rspos     = (int2*)alloc((size_t)NPOS * 8);
  int*    bcnt      = (int*)alloc(NBUK * 4);
  int*    bfill     = (int*)alloc(NBUK * 4);
  int*    bbase     = (int*)alloc((NBUK + 1) * 4);
  uint16_t* B1 = (uint16_t*)alloc(128 * 256 * 2);
  uint16_t* B2 = (uint16_t*)alloc(128 * 256 * 2);
  uint16_t* B3 = (uint16_t*)alloc(128 * 256 * 2);
  uint16_t* Wlb = (uint16_t*)alloc(48 * 384 * 2);
  char* xb2 = x0p;   // alias: x0p dead after layer-1 GEMM

  const int TB = (NE + 8191) / 8192;      // 196 tiles
  const int NB = (NN + 255) / 256;        // 391
  const int EB = (NE + 255) / 256;        // 6250

  hipMemsetAsync(bcnt, 0, NBUK * 4, stream);
  pack_weights<<<384, 256, 0, stream>>>(W1r, W1o, W2r, W2o, W3r, W3o, B1, B2, B3);
  pack_wl<<<72, 256, 0, stream>>>(Wl, Wlb);
  bucket_hist<<<TB, 512, 0, stream>>>(dst, bcnt);
  bucket_scan<<<1, 512, 0, stream>>>(bcnt, bfill, bbase);
  binscat<<<TB, 512, 0, stream>>>(src, dst, ew, bfill, ebin);
  bucket_csr<<<NBUK, 256, 0, stream>>>(ebin, bbase, row_start, epack, perm);
  ipos_build<<<NB, 256, 0, stream>>>(perm, ipos);
  epack_remap<<<EB, 256, 0, stream>>>(epack, ipos);
  rspos_build<<<(NPOS + 255) / 256, 256, 0, stream>>>(row_start, perm, rspos);
  pad_x0<<<NN / 4, 256, 0, stream>>>(x0, perm, x0p);

  const int SG = (NPOS / 64) * 8;         // 1563 groups x 8 slices
  spmm_kernel<<<SG, 256, 0, stream>>>(x0p, rspos, epack, agg);
  gemm_kernel<<<(NN + 127) / 128, 256, 0, stream>>>(agg, x0p, B1, b1, xb1);
  spmm_kernel<<<SG, 256, 0, stream>>>(xb1, rspos, epack, agg);
  gemm_kernel<<<(NN + 127) / 128, 256, 0, stream>>>(agg, xb1, B2, b2, xb2);
  spmm_kernel<<<SG, 256, 0, stream>>>(xb2, rspos, epack, agg);
  gemm_kernel<<<(NN + 127) / 128, 256, 0, stream>>>(agg, xb2, B3, b3, xb3);

  final_kernel<<<(NN + 63) / 64, 256, 0, stream>>>(xb1, xb2, xb3, Wlb, bl, perm, (float*)d_out);
}

// Round 11
// 557.447 us; speedup vs baseline: 1.1523x; 1.1523x over previous
//
#include <hip/hip_runtime.h>
#include <hip/hip_bf16.h>
#include <stdint.h>

#define NN 100000
#define NE 1600000
#define FIN 100
#define HID 128
#define CLS 47
#define NBUK 391            // ceil(NN/256) buckets of 256 nodes
#define NPOS 100032         // NN padded to 64
#define SLB ((size_t)NN * 32)   // bytes per 16-col slice of one activation matrix

typedef __attribute__((ext_vector_type(8))) short bf16x8;
typedef __attribute__((ext_vector_type(4))) float f32x4;

#define AS1(p) ((const __attribute__((address_space(1))) void*)(p))
#define AS3(p) ((__attribute__((address_space(3))) void*)(p))

__device__ __forceinline__ uint16_t f2bf(float f) {
  union { float f; uint32_t u; } v; v.f = f;
  uint32_t r = v.u + 0x7fffu + ((v.u >> 16) & 1u);
  return (uint16_t)(r >> 16);
}

// sliced positional layout: element (pos, col) at base + (col>>4)*SLB + pos*32 + (col&15)*2
__device__ __forceinline__ const char* xsrc(const char* base, int row, int col) {
  return base + (size_t)(col >> 4) * SLB + (size_t)row * 32 + (size_t)(col & 15) * 2;
}
__device__ __forceinline__ char* xdst(char* base, int row, int col) {
  return base + (size_t)(col >> 4) * SLB + (size_t)row * 32 + (size_t)(col & 15) * 2;
}

// ---- weight packing: B_l[j][k] (128 x 256) bf16; k<128 -> W_rel, k>=128 -> W_root (layer1 zero-padded)
__global__ void pack_weights(const float* __restrict__ W1r, const float* __restrict__ W1o,
                             const float* __restrict__ W2r, const float* __restrict__ W2o,
                             const float* __restrict__ W3r, const float* __restrict__ W3o,
                             uint16_t* __restrict__ B1, uint16_t* __restrict__ B2, uint16_t* __restrict__ B3) {
  int idx = blockIdx.x * 256 + threadIdx.x;      // < 3*128*256
  int l = idx >> 15;
  int rem = idx & 32767;
  int j = rem >> 8;
  int k = rem & 255;
  if (l == 0) {
    uint16_t v = 0;
    if (k < FIN) v = f2bf(W1r[j*FIN + k]);
    else if (k >= 128 && k < 128 + FIN) v = f2bf(W1o[j*FIN + (k - 128)]);
    B1[j*256 + k] = v;
  } else if (l == 1) {
    B2[j*256 + k] = (k < 128) ? f2bf(W2r[j*128 + k]) : f2bf(W2o[j*128 + (k - 128)]);
  } else {
    B3[j*256 + k] = (k < 128) ? f2bf(W3r[j*128 + k]) : f2bf(W3o[j*128 + (k - 128)]);
  }
}

// ---- W_lin [47,384] f32 -> Wlb [48,384] bf16 (row 47 zero)
__global__ void pack_wl(const float* __restrict__ Wl, uint16_t* __restrict__ Wlb) {
  int idx = blockIdx.x * 256 + threadIdx.x;      // < 48*384
  int r = idx / 384;
  int c = idx - r * 384;
  Wlb[idx] = (r < CLS) ? f2bf(Wl[r*384 + c]) : (uint16_t)0;
}

// ---- pad+convert x0 row perm[p] -> position p, sliced bf16; 4 positions/block
__global__ __launch_bounds__(256) void pad_x0(const float* __restrict__ x0, const int* __restrict__ perm,
                                              char* __restrict__ xs) {
  int p = blockIdx.x * 4 + (threadIdx.x >> 6);   // grid = NN/4 exactly
  int n = perm[p];
  int c = 2 * (threadIdx.x & 63);
  uint32_t o = 0;
  if (c < FIN) {
    float2 v = *(const float2*)(x0 + (size_t)n*FIN + c);
    o = ((uint32_t)f2bf(v.y) << 16) | (uint32_t)f2bf(v.x);
  }
  *(uint32_t*)xdst(xs, p, c) = o;
}

// ======== binned CSR build ========
__global__ __launch_bounds__(512) void bucket_hist(const int* __restrict__ dst, int* __restrict__ bcnt) {
  __shared__ int h[NBUK];
  int tid = threadIdx.x;
  for (int i = tid; i < NBUK; i += 512) h[i] = 0;
  __syncthreads();
  int tile0 = blockIdx.x * 8192;
  int n = NE - tile0; if (n > 8192) n = 8192;
  for (int i = tid; i < n; i += 512) atomicAdd(&h[dst[tile0 + i] >> 8], 1);
  __syncthreads();
  for (int i = tid; i < NBUK; i += 512) if (h[i]) atomicAdd(&bcnt[i], h[i]);
}

__global__ __launch_bounds__(512) void bucket_scan(const int* __restrict__ bcnt,
                                                   int* __restrict__ bfill, int* __restrict__ bbase) {
  __shared__ int sh[512];
  int t = threadIdx.x;
  int v = (t < NBUK) ? bcnt[t] : 0;
  sh[t] = v;
  __syncthreads();
  for (int off = 1; off < 512; off <<= 1) {
    int tv = (t >= off) ? sh[t - off] : 0;
    __syncthreads();
    sh[t] += tv;
    __syncthreads();
  }
  if (t < NBUK) {
    int e = sh[t] - v;
    bfill[t] = e;
    bbase[t] = e;
  }
  if (t == 0) bbase[NBUK] = NE;
}

// Packed rec: x = src | dstLocal<<17 (src<2^17, dstLocal<256), y = weight bits.
__global__ __launch_bounds__(512) void binscat(const int* __restrict__ src, const int* __restrict__ dst,
                                               const float* __restrict__ ew,
                                               int* __restrict__ bfill, int2* __restrict__ ebin) {
  __shared__ int h[NBUK];
  __shared__ int base[NBUK];
  int tid = threadIdx.x;
  for (int i = tid; i < NBUK; i += 512) h[i] = 0;
  __syncthreads();
  int tile0 = blockIdx.x * 8192;
  int n = NE - tile0; if (n > 8192) n = 8192;
  for (int i = tid; i < n; i += 512) atomicAdd(&h[dst[tile0 + i] >> 8], 1);
  __syncthreads();
  for (int i = tid; i < NBUK; i += 512) base[i] = h[i] ? atomicAdd(&bfill[i], h[i]) : 0;
  __syncthreads();
  for (int i = tid; i < NBUK; i += 512) h[i] = 0;
  __syncthreads();
  for (int i = tid; i < n; i += 512) {
    int e = tile0 + i;
    int d = dst[e];
    int b = d >> 8;
    int r = atomicAdd(&h[b], 1);
    ebin[base[b] + r] = make_int2(src[e] | ((d & 255) << 17), __float_as_int(ew[e]));
  }
}

// Stage 4: one block per bucket. Degree-sorts the bucket's nodes into positions,
// emits epack in POSITION order (so a spmm wave's 8 nodes read adjacent rec
// streams), plus rspos[pos]={start,deg}, perm[pos]=node, ipos[node]=pos.
//   epack = src<<15 | bf16(w)   (w>=0: lossless 15-bit bf16 store)
__global__ __launch_bounds__(256) void bucket_csr(const int2* __restrict__ ebin,
                                                  const int* __restrict__ bbase,
                                                  uint32_t* __restrict__ epack,
                                                  int* __restrict__ perm,
                                                  int* __restrict__ ipos,
                                                  int2* __restrict__ rspos) {
  __shared__ int sh[256];
  __shared__ int deg_q[256];
  __shared__ int rank_of[256];
  __shared__ int fill[256];
  __shared__ int dh[64];
  __shared__ int doff[64];
  int b = blockIdx.x;
  int tid = threadIdx.x;
  int ebase = bbase[b], eend = bbase[b + 1];
  int cnt = eend - ebase;
  int nvalid = NN - b * 256; if (nvalid > 256) nvalid = 256;
  sh[tid] = 0;
  deg_q[tid] = 0;
  if (tid < 64) dh[tid] = 0;
  __syncthreads();
  for (int i = tid; i < cnt; i += 256) atomicAdd(&sh[(uint32_t)ebin[ebase + i].x >> 17], 1);
  __syncthreads();
  int histv = sh[tid];                 // degree of local node tid
  int node = b * 256 + tid;
  bool valid = node < NN;
  int dbin = histv > 63 ? 63 : histv;
  int lrank = 0;
  if (valid) lrank = atomicAdd(&dh[dbin], 1);
  __syncthreads();
  if (tid < 64) {
    int v = dh[tid];
    int x = v;
    #pragma unroll
    for (int off = 1; off < 64; off <<= 1) {
      int y = __shfl_up(x, off, 64);
      if (tid >= off) x += y;
    }
    doff[tid] = x - v;
  }
  __syncthreads();
  int q = doff[dbin] + lrank;          // position rank within bucket
  if (valid) {
    deg_q[q] = histv;
    rank_of[tid] = q;
    perm[b * 256 + q] = node;
    ipos[node] = b * 256 + q;
  }
  __syncthreads();
  // scan degrees in position order -> per-position edge offsets
  sh[tid] = deg_q[tid];
  __syncthreads();
  for (int off = 1; off < 256; off <<= 1) {
    int tv = (tid >= off) ? sh[tid - off] : 0;
    __syncthreads();
    sh[tid] += tv;
    __syncthreads();
  }
  int posexcl = sh[tid] - deg_q[tid];
  fill[tid] = ebase + posexcl;         // cursor indexed by position rank
  int pos = b * 256 + tid;
  if (pos < NPOS)
    rspos[pos] = (tid < nvalid) ? make_int2(ebase + posexcl, deg_q[tid]) : make_int2(0, 0);
  __syncthreads();
  for (int i = tid; i < cnt; i += 256) {
    int2 rec = ebin[ebase + i];
    int dl = (uint32_t)rec.x >> 17;
    uint32_t s = (uint32_t)rec.x & 0x1FFFFu;
    int pp = atomicAdd(&fill[rank_of[dl]], 1);
    epack[pp] = (s << 15) | (uint32_t)f2bf(__int_as_float(rec.y));
  }
}

// ---- remap epack src node -> position (positions are what spmm gathers)
__global__ void epack_remap(uint32_t* __restrict__ epack, const int* __restrict__ ipos) {
  int e = blockIdx.x * 256 + threadIdx.x;
  if (e < NE) {
    uint32_t rec = epack[e];
    epack[e] = ((uint32_t)ipos[rec >> 15] << 15) | (rec & 0x7FFFu);
  }
}

// ---- SpMM (XCD-sliced, positional): agg[p, slice s] = sum_e w_e * x[srcpos_e, slice s]
// 8 nodes/wave x 8 lanes x 4B -> 100k waves (TLP is what hides gather latency;
// round-10's 16-node layout halved waves and regressed). epack is position-
// ordered, so the wave's 8 rec streams live in one ~512B window (L1-hot).
// Unclamped epack reads (guard page); garbage recs killed by w=0, boff mask
// keeps gathers inside the workspace.
__global__ __launch_bounds__(256) void spmm_kernel(const char* __restrict__ xs,
                                                   const int2* __restrict__ rspos,
                                                   const uint32_t* __restrict__ epack,
                                                   char* __restrict__ aggs) {
  int b = blockIdx.x;
  int s = b & 7;
  int g = b >> 3;
  int lane = threadIdx.x & 63;
  int wave = threadIdx.x >> 6;
  int nu = lane >> 3;
  int c4 = (lane & 7) * 4;
  const char* xsl = xs + (size_t)s * SLB;
  char* asl = aggs + (size_t)s * SLB;
  int p = g * 32 + wave * 8 + nu;      // g < NPOS/32
  int2 rs = rspos[p];
  int rs0 = rs.x, d = rs.y;

  float a0 = 0.f, a1 = 0.f;
  for (int j = 0; ; j += 8) {
    if (!__ballot(j < d)) break;
    uint32_t rec[8];
    const uint32_t* ep = epack + rs0 + j;
    #pragma unroll
    for (int u = 0; u < 8; ++u) rec[u] = ep[u];
    uint32_t pair[8];
    #pragma unroll
    for (int u = 0; u < 8; ++u) {
      uint32_t boff = (rec[u] >> 10) & 0x003FFFE0u;   // srcpos*32
      pair[u] = *(const uint32_t*)(xsl + boff + c4);
    }
    #pragma unroll
    for (int u = 0; u < 8; ++u) {
      float w = __int_as_float((rec[u] << 16) & 0x7FFF0000u);
      if (j + u >= d) w = 0.f;
      union { uint32_t u32; float f; } lo, hi;
      lo.u32 = pair[u] << 16; hi.u32 = pair[u] & 0xFFFF0000u;
      a0 += w * lo.f;
      a1 += w * hi.f;
    }
  }
  if (p < NN) {
    uint32_t o = ((uint32_t)f2bf(a1) << 16) | (uint32_t)f2bf(a0);
    *(uint32_t*)(asl + (size_t)p * 32 + c4) = o;   // 256B coalesced per wave
  }
}

// ---- fused GEMM: out = relu([A1|A2] @ B^T + bias); positional sliced bf16 in/out
__global__ __launch_bounds__(256) void gemm_kernel(const char* __restrict__ A1, const char* __restrict__ A2,
                                                   const uint16_t* __restrict__ Bm, const float* __restrict__ bias,
                                                   char* __restrict__ out) {
  __shared__ uint16_t ldsA[128 * 32];
  __shared__ uint16_t ldsB[128 * 32];
  int t = threadIdx.x;
  int n0 = blockIdx.x * 128;
  int lane = t & 63, wave = t >> 6;
  int wm = (wave >> 1) * 64, wn = (wave & 1) * 64;
  int l15 = lane & 15, quad = lane >> 4;

  f32x4 acc[4][4];
  #pragma unroll
  for (int i = 0; i < 4; ++i)
    #pragma unroll
    for (int j = 0; j < 4; ++j) acc[i][j] = (f32x4){0.f, 0.f, 0.f, 0.f};

  for (int kt = 0; kt < 8; ++kt) {
    int kbase = kt * 32;
    const char* Asrc = (kbase < 128) ? A1 : A2;
    int klocal = kbase & 127;
    #pragma unroll
    for (int q = 0; q < 2; ++q) {
      int u = t + q * 256;                 // 0..511
      int r = u >> 2;                      // 0..127
      int kg = (u & 3) * 8;
      int rowA = n0 + r; if (rowA >= NN) rowA = NN - 1;
      __builtin_amdgcn_global_load_lds(AS1(xsrc(Asrc, rowA, klocal + kg)), AS3(&ldsA[u * 8]), 16, 0, 0);
      __builtin_amdgcn_global_load_lds(AS1(Bm + r*256 + kbase + kg), AS3(&ldsB[u * 8]), 16, 0, 0);
    }
    __syncthreads();
    bf16x8 af[4], bfr[4];
    #pragma unroll
    for (int mi = 0; mi < 4; ++mi) af[mi] = *(const bf16x8*)&ldsA[(wm + mi*16 + l15) * 32 + quad * 8];
    #pragma unroll
    for (int ni = 0; ni < 4; ++ni) bfr[ni] = *(const bf16x8*)&ldsB[(wn + ni*16 + l15) * 32 + quad * 8];
    #pragma unroll
    for (int mi = 0; mi < 4; ++mi)
      #pragma unroll
      for (int ni = 0; ni < 4; ++ni)
        acc[mi][ni] = __builtin_amdgcn_mfma_f32_16x16x32_bf16(af[mi], bfr[ni], acc[mi][ni], 0, 0, 0);
    __syncthreads();
  }

  #pragma unroll
  for (int mi = 0; mi < 4; ++mi) {
    #pragma unroll
    for (int ni = 0; ni < 4; ++ni) {
      int c = wn + ni*16 + l15;
      float bc = bias[c];
      #pragma unroll
      for (int i = 0; i < 4; ++i) {
        int r = n0 + wm + mi*16 + quad*4 + i;
        if (r < NN) {
          float v = acc[mi][ni][i] + bc;
          v = v > 0.f ? v : 0.f;
          *(uint16_t*)xdst(out, r, c) = f2bf(v);
        }
      }
    }
  }
}

// ---- final: positional rows; output row mapped back through perm
__global__ __launch_bounds__(256) void final_kernel(const char* __restrict__ x1, const char* __restrict__ x2,
                                                    const char* __restrict__ x3,
                                                    const uint16_t* __restrict__ Wlb, const float* __restrict__ bl,
                                                    const int* __restrict__ perm,
                                                    float* __restrict__ out) {
  int t = threadIdx.x;
  int lane = t & 63, wave = t >> 6;
  int n0 = blockIdx.x * 64 + wave * 16;
  int l15 = lane & 15, quad = lane >> 4;

  f32x4 acc[3];
  #pragma unroll
  for (int i = 0; i < 3; ++i) acc[i] = (f32x4){0.f, 0.f, 0.f, 0.f};

  int arow = n0 + l15; if (arow >= NN) arow = NN - 1;

  #pragma unroll
  for (int kt = 0; kt < 12; ++kt) {
    const char* xs = (kt < 4) ? x1 : (kt < 8) ? x2 : x3;
    int klocal = (kt & 3) * 32 + quad * 8;
    bf16x8 af = *(const bf16x8*)xsrc(xs, arow, klocal);
    int kglob = kt * 32 + quad * 8;
    #pragma unroll
    for (int nt = 0; nt < 3; ++nt) {
      int c = nt*16 + l15;                 // < 48, row 47 of Wlb is zero
      bf16x8 bfr = *(const bf16x8*)(Wlb + (size_t)c*(3*HID) + kglob);
      acc[nt] = __builtin_amdgcn_mfma_f32_16x16x32_bf16(af, bfr, acc[nt], 0, 0, 0);
    }
  }

  float bias[3]; bool valid[3];
  #pragma unroll
  for (int nt = 0; nt < 3; ++nt) {
    int c = nt*16 + l15;
    valid[nt] = (c < CLS);
    bias[nt] = valid[nt] ? bl[c] : 0.f;
  }

  #pragma unroll
  for (int i = 0; i < 4; ++i) {
    int r = n0 + quad*4 + i;
    float v0 = acc[0][i] + bias[0];
    float v1 = acc[1][i] + bias[1];
    float v2 = valid[2] ? (acc[2][i] + bias[2]) : -INFINITY;
    float m = fmaxf(v0, fmaxf(v1, v2));
    #pragma unroll
    for (int off = 8; off >= 1; off >>= 1) m = fmaxf(m, __shfl_xor(m, off, 64));
    float s = __expf(v0 - m) + __expf(v1 - m) + (valid[2] ? __expf(v2 - m) : 0.f);
    #pragma unroll
    for (int off = 8; off >= 1; off >>= 1) s += __shfl_xor(s, off, 64);
    float lse = m + __logf(s);
    if (r < NN) {
      int n = perm[r];
      out[(size_t)n*CLS + l15]      = v0 - lse;
      out[(size_t)n*CLS + 16 + l15] = v1 - lse;
      if (valid[2]) out[(size_t)n*CLS + 32 + l15] = v2 - lse;
    }
  }
}

extern "C" void kernel_launch(void* const* d_in, const int* in_sizes, int n_in,
                              void* d_out, int out_size, void* d_ws, size_t ws_size,
                              hipStream_t stream) {
  (void)in_sizes; (void)n_in; (void)out_size; (void)ws_size;
  const float* x0  = (const float*)d_in[0];
  const int*   ei  = (const int*)d_in[1];
  const float* ew  = (const float*)d_in[2];
  const float* W1r = (const float*)d_in[3];
  const float* W1o = (const float*)d_in[4];
  const float* b1  = (const float*)d_in[5];
  const float* W2r = (const float*)d_in[6];
  const float* W2o = (const float*)d_in[7];
  const float* b2  = (const float*)d_in[8];
  const float* W3r = (const float*)d_in[9];
  const float* W3o = (const float*)d_in[10];
  const float* b3  = (const float*)d_in[11];
  const float* Wl  = (const float*)d_in[12];
  const float* bl  = (const float*)d_in[13];
  const int* src = ei;
  const int* dst = ei + NE;

  char* ws = (char*)d_ws;
  size_t off = 0;
  auto alloc = [&](size_t bytes) -> void* {
    void* p = ws + off;
    off += (bytes + 255) & ~(size_t)255;
    return p;
  };
  char* x0p = (char*)alloc(SLB * 8);   // positional sliced activations; reused as xb2
  char* xb1 = (char*)alloc(SLB * 8);
  char* xb3 = (char*)alloc(SLB * 8);
  char* agg = (char*)alloc(SLB * 8);
  uint32_t* epack    = (uint32_t*)alloc((size_t)NE * 4 + 512);  // +guard for unclamped reads
  int2*   ebin      = (int2*)alloc((size_t)NE * 8);
  int*    perm      = (int*)alloc((size_t)NN * 4);
  int*    ipos      = (int*)alloc((size_t)NN * 4);
  int2*   rspos     = (int2*)alloc((size_t)NPOS * 8);
  int*    bcnt      = (int*)alloc(NBUK * 4);
  int*    bfill     = (int*)alloc(NBUK * 4);
  int*    bbase     = (int*)alloc((NBUK + 1) * 4);
  uint16_t* B1 = (uint16_t*)alloc(128 * 256 * 2);
  uint16_t* B2 = (uint16_t*)alloc(128 * 256 * 2);
  uint16_t* B3 = (uint16_t*)alloc(128 * 256 * 2);
  uint16_t* Wlb = (uint16_t*)alloc(48 * 384 * 2);
  char* xb2 = x0p;   // alias: x0p dead after layer-1 GEMM

  const int TB = (NE + 8191) / 8192;      // 196 tiles
  const int EB = (NE + 255) / 256;        // 6250

  hipMemsetAsync(bcnt, 0, NBUK * 4, stream);
  pack_weights<<<384, 256, 0, stream>>>(W1r, W1o, W2r, W2o, W3r, W3o, B1, B2, B3);
  pack_wl<<<72, 256, 0, stream>>>(Wl, Wlb);
  bucket_hist<<<TB, 512, 0, stream>>>(dst, bcnt);
  bucket_scan<<<1, 512, 0, stream>>>(bcnt, bfill, bbase);
  binscat<<<TB, 512, 0, stream>>>(src, dst, ew, bfill, ebin);
  bucket_csr<<<NBUK, 256, 0, stream>>>(ebin, bbase, epack, perm, ipos, rspos);
  epack_remap<<<EB, 256, 0, stream>>>(epack, ipos);
  pad_x0<<<NN / 4, 256, 0, stream>>>(x0, perm, x0p);

  const int SG = (NPOS / 32) * 8;         // 3126 groups x 8 slices = 25008 blocks
  spmm_kernel<<<SG, 256, 0, stream>>>(x0p, rspos, epack, agg);
  gemm_kernel<<<(NN + 127) / 128, 256, 0, stream>>>(agg, x0p, B1, b1, xb1);
  spmm_kernel<<<SG, 256, 0, stream>>>(xb1, rspos, epack, agg);
  gemm_kernel<<<(NN + 127) / 128, 256, 0, stream>>>(agg, xb1, B2, b2, xb2);
  spmm_kernel<<<SG, 256, 0, stream>>>(xb2, rspos, epack, agg);
  gemm_kernel<<<(NN + 127) / 128, 256, 0, stream>>>(agg, xb2, B3, b3, xb3);

  final_kernel<<<(NN + 63) / 64, 256, 0, stream>>>(xb1, xb2, xb3, Wlb, bl, perm, (float*)d_out);
}